// Round 1
// 703.895 us; speedup vs baseline: 1.0038x; 1.0038x over previous
//
#include <hip/hip_runtime.h>
#include <hip/hip_bf16.h>
#include <math.h>

#define NCLS 64
#define FDIM 256
#define EPS_F 1e-8f
#define NQ 131072
#define NS 262144

typedef __attribute__((ext_vector_type(8))) short short8;
typedef __attribute__((ext_vector_type(4))) float f32x4;

__device__ __forceinline__ unsigned short bf16bits(float f) {
    __hip_bfloat16 h = __float2bfloat16(f);
    return *reinterpret_cast<unsigned short*>(&h);
}

// ---------------------------------------------------------------------------
// Kernel A: segment-sum. 256 blocks x 1024 threads (16 waves), 1024 rows/blk.
//
// Round-4 diagnosis: atomicAdd(float*) on LDS was NOT ds_add_f32 — counters
// (359us, VALUBusy 0.53%, HBM 5.4%, LDS_BANK_CONFLICT 0, VGPR 24) show
// ~210 cyc per LDS atomic with every pipe idle = CAS-loop expansion with
// dependent ~120cyc LDS round-trips + cross-wave retry storms.
//
// Fix: raw ds_add_f32 (fire-and-forget HW f32 LDS atomic) via inline asm.
// Layout: lane owns dim-COLUMNS {l, 64+l, 128+l, 192+l} so the scatter is
// sacc[cc*256 + k*64 + l]: bank = l&31 (2-way = free, m136) and k*256B is a
// static offset: immediate. Loads: 4x global_load_dword per row (256 B
// coalesced each); 16 loads/chunk in flight per wave x 16 waves >> the
// ~9 KB/CU Little's-law requirement at HBM latency.
// Label broadcast via v_readlane (SALU) — the hot loop issues NO lgkm ops
// except the ds_adds themselves. Explicit s_waitcnt lgkmcnt(0) + memory
// clobber before the final barrier (compiler can't count asm DS ops).
// ---------------------------------------------------------------------------
__global__ __launch_bounds__(1024) void seg_sum_kernel(
    const float* __restrict__ support, const int* __restrict__ labels,
    float* __restrict__ pa, int set_mask)
{
    __shared__ float sacc[NCLS * FDIM];   // 64 KB exactly
    const int tid = threadIdx.x;
    #pragma unroll
    for (int i = 0; i < 16; ++i) sacc[tid + i * 1024] = 0.0f;
    __syncthreads();

    const int lane = tid & 63;
    const int wave = tid >> 6;
    const int wbase = blockIdx.x * 1024 + wave * 64;   // this wave's 64 rows
    const int mylab = labels[wbase + lane] & (NCLS - 1);

    float* dst = pa + (size_t)(blockIdx.x & set_mask) * 16448;
    unsafeAtomicAdd(&dst[16384 + mylab], 1.0f);        // count, 1 per row

    // Column ownership: lane l covers dims {l, 64+l, 128+l, 192+l} of a row.
    const float* cp = support + (size_t)wbase * FDIM + lane;
    // LDS byte base for this lane (aperture is 4GiB-aligned: low 32 bits of
    // the generic address of a __shared__ object ARE the LDS byte offset).
    const unsigned sbase = (unsigned)(uintptr_t)(&sacc[0]) + ((unsigned)lane << 2);

    float cur[4][4], nxt[4][4];
    #pragma unroll
    for (int j = 0; j < 4; ++j) {
        const float* rp = cp + (size_t)j * FDIM;
        cur[j][0] = rp[0];   cur[j][1] = rp[64];
        cur[j][2] = rp[128]; cur[j][3] = rp[192];
    }

    #pragma unroll 1
    for (int ch = 0; ch < 16; ++ch) {
        if (ch < 15) {
            #pragma unroll
            for (int j = 0; j < 4; ++j) {
                const float* rp = cp + (size_t)(ch * 4 + 4 + j) * FDIM;
                nxt[j][0] = rp[0];   nxt[j][1] = rp[64];
                nxt[j][2] = rp[128]; nxt[j][3] = rp[192];
            }
        }
        #pragma unroll
        for (int j = 0; j < 4; ++j) {
            const int cc = __builtin_amdgcn_readlane(mylab, ch * 4 + j);
            const unsigned ab = sbase + ((unsigned)cc << 10);
            asm volatile("ds_add_f32 %0, %1"            :: "v"(ab), "v"(cur[j][0]));
            asm volatile("ds_add_f32 %0, %1 offset:256" :: "v"(ab), "v"(cur[j][1]));
            asm volatile("ds_add_f32 %0, %1 offset:512" :: "v"(ab), "v"(cur[j][2]));
            asm volatile("ds_add_f32 %0, %1 offset:768" :: "v"(ab), "v"(cur[j][3]));
        }
        #pragma unroll
        for (int j = 0; j < 4; ++j) {
            cur[j][0] = nxt[j][0]; cur[j][1] = nxt[j][1];
            cur[j][2] = nxt[j][2]; cur[j][3] = nxt[j][3];
        }
    }

    // Drain our (compiler-invisible) ds_adds before anyone reads sacc; the
    // memory clobber also blocks store-to-load forwarding of the zero-init.
    asm volatile("s_waitcnt lgkmcnt(0)" ::: "memory");
    __syncthreads();

    #pragma unroll
    for (int i = 0; i < 16; ++i)
        unsafeAtomicAdd(&dst[tid + i * 1024], sacc[tid + i * 1024]);
}

// ---------------------------------------------------------------------------
// Kernel B: sum npart partials, normalize, emit Pn as bf16 B-FRAGMENTS for
// mfma_f32_16x16x32_bf16 (unchanged — verified correct).
// ---------------------------------------------------------------------------
__global__ __launch_bounds__(256) void proto_norm_kernel(
    const float* __restrict__ pa, int npart, uint4* __restrict__ pn_frags)
{
    __shared__ float pvec[FDIM];
    __shared__ float ssum[4];
    const int c = blockIdx.x;
    const int d = threadIdx.x;
    const int lane = d & 63;
    const int wv = d >> 6;

    float sum = 0.0f;
    #pragma unroll
    for (int s = 0; s < 16; ++s)
        if (s < npart) sum += pa[(size_t)s * 16448 + c * FDIM + d];

    float cv = (lane < npart) ? pa[(size_t)lane * 16448 + 16384 + c] : 0.0f;
    cv += __shfl_xor(cv, 1); cv += __shfl_xor(cv, 2);
    cv += __shfl_xor(cv, 4); cv += __shfl_xor(cv, 8);
    const float cnt = __shfl(cv, 0);

    const float p = sum / fmaxf(cnt, 1.0f);

    float ss = p * p;
    ss += __shfl_xor(ss, 1);  ss += __shfl_xor(ss, 2);
    ss += __shfl_xor(ss, 4);  ss += __shfl_xor(ss, 8);
    ss += __shfl_xor(ss, 16); ss += __shfl_xor(ss, 32);
    if (lane == 0) ssum[wv] = ss;
    __syncthreads();
    const float tot = ssum[0] + ssum[1] + ssum[2] + ssum[3];
    const float innv = 1.0f / fmaxf(sqrtf(tot), EPS_F);
    pvec[d] = p * innv;
    __syncthreads();

    if (d < 32) {
        const int kc = d >> 2, quad = d & 3;
        const float* pp = &pvec[kc * 32 + quad * 8];
        uint w0 = bf16bits(pp[0]) | ((uint)bf16bits(pp[1]) << 16);
        uint w1 = bf16bits(pp[2]) | ((uint)bf16bits(pp[3]) << 16);
        uint w2 = bf16bits(pp[4]) | ((uint)bf16bits(pp[5]) << 16);
        uint w3 = bf16bits(pp[6]) | ((uint)bf16bits(pp[7]) << 16);
        pn_frags[((c >> 4) * 8 + kc) * 64 + (c & 15) + 16 * quad] =
            make_uint4(w0, w1, w2, w3);
    }
}

// ---------------------------------------------------------------------------
// Kernel C: MFMA query GEMM + fused log_softmax (unchanged this round —
// expected ~330us, counters hidden below top-5; target next round once
// seg_sum is off the top of the profile).
// ---------------------------------------------------------------------------
#define QSTR 272   // bf16 elements per LDS row (544 B, multiple of 16 B)

__global__ __launch_bounds__(256) void query_kernel(
    const float* __restrict__ query, const uint4* __restrict__ pn_frags,
    float* __restrict__ out)
{
    __shared__ unsigned short Qb[64 * QSTR];   // 34816 B
    const int tid = threadIdx.x;
    const int lane = tid & 63;
    const int wave = tid >> 6;
    const size_t qb0 = (size_t)blockIdx.x * 64;

    // Stage: iteration i handles row i*4+wave; 64 lanes cover the whole row.
    #pragma unroll
    for (int i = 0; i < 16; ++i) {
        const int row = i * 4 + wave;
        const float4 v = ((const float4*)(query + (qb0 + row) * FDIM))[lane];
        const uint lo = bf16bits(v.x) | ((uint)bf16bits(v.y) << 16);
        const uint hi = bf16bits(v.z) | ((uint)bf16bits(v.w) << 16);
        *(uint2*)&Qb[row * QSTR + lane * 4] = make_uint2(lo, hi);
    }
    __syncthreads();

    const int m = lane & 15;
    const int quad = lane >> 4;
    const unsigned short* arow = &Qb[(wave * 16 + m) * QSTR + quad * 8];
    const short8* bp = (const short8*)pn_frags;

    f32x4 acc0 = {0.f,0.f,0.f,0.f}, acc1 = {0.f,0.f,0.f,0.f};
    f32x4 acc2 = {0.f,0.f,0.f,0.f}, acc3 = {0.f,0.f,0.f,0.f};
    float ssq = 0.0f;

    short8 a  = *(const short8*)(arow);
    short8 b0 = bp[(0 * 8 + 0) * 64 + lane];
    short8 b1 = bp[(1 * 8 + 0) * 64 + lane];
    short8 b2 = bp[(2 * 8 + 0) * 64 + lane];
    short8 b3 = bp[(3 * 8 + 0) * 64 + lane];

    #pragma unroll
    for (int kc = 0; kc < 8; ++kc) {
        short8 an, c0, c1, c2, c3;
        const int kn = (kc < 7) ? kc + 1 : 7;
        an = *(const short8*)(arow + kn * 32);
        c0 = bp[(0 * 8 + kn) * 64 + lane];
        c1 = bp[(1 * 8 + kn) * 64 + lane];
        c2 = bp[(2 * 8 + kn) * 64 + lane];
        c3 = bp[(3 * 8 + kn) * 64 + lane];

        // ||q|| partial from this lane's 8 bf16 elements (row m, quad slice).
        float x0 = __uint_as_float(((uint)(unsigned short)a[0]) << 16);
        float x1 = __uint_as_float(((uint)(unsigned short)a[1]) << 16);
        float x2 = __uint_as_float(((uint)(unsigned short)a[2]) << 16);
        float x3 = __uint_as_float(((uint)(unsigned short)a[3]) << 16);
        float x4 = __uint_as_float(((uint)(unsigned short)a[4]) << 16);
        float x5 = __uint_as_float(((uint)(unsigned short)a[5]) << 16);
        float x6 = __uint_as_float(((uint)(unsigned short)a[6]) << 16);
        float x7 = __uint_as_float(((uint)(unsigned short)a[7]) << 16);
        ssq = fmaf(x0, x0, ssq); ssq = fmaf(x1, x1, ssq);
        ssq = fmaf(x2, x2, ssq); ssq = fmaf(x3, x3, ssq);
        ssq = fmaf(x4, x4, ssq); ssq = fmaf(x5, x5, ssq);
        ssq = fmaf(x6, x6, ssq); ssq = fmaf(x7, x7, ssq);

        acc0 = __builtin_amdgcn_mfma_f32_16x16x32_bf16(a, b0, acc0, 0, 0, 0);
        acc1 = __builtin_amdgcn_mfma_f32_16x16x32_bf16(a, b1, acc1, 0, 0, 0);
        acc2 = __builtin_amdgcn_mfma_f32_16x16x32_bf16(a, b2, acc2, 0, 0, 0);
        acc3 = __builtin_amdgcn_mfma_f32_16x16x32_bf16(a, b3, acc3, 0, 0, 0);

        a = an; b0 = c0; b1 = c1; b2 = c2; b3 = c3;
    }

    // Combine quad slices: lane ends with full ssq of query row (lane&15).
    ssq += __shfl_xor(ssq, 16);
    ssq += __shfl_xor(ssq, 32);

    const size_t qbw = qb0 + wave * 16;
    #pragma unroll
    for (int reg = 0; reg < 4; ++reg) {
        const float rssq = __shfl(ssq, quad * 4 + reg);
        const float qs = 1.0f / fmaxf(sqrtf(rssq), EPS_F);
        float s0 = acc0[reg] * qs;
        float s1 = acc1[reg] * qs;
        float s2 = acc2[reg] * qs;
        float s3 = acc3[reg] * qs;
        float mx = fmaxf(fmaxf(s0, s1), fmaxf(s2, s3));
        mx = fmaxf(mx, __shfl_xor(mx, 1));
        mx = fmaxf(mx, __shfl_xor(mx, 2));
        mx = fmaxf(mx, __shfl_xor(mx, 4));
        mx = fmaxf(mx, __shfl_xor(mx, 8));
        float e = __expf(s0 - mx) + __expf(s1 - mx) +
                  __expf(s2 - mx) + __expf(s3 - mx);
        e += __shfl_xor(e, 1);
        e += __shfl_xor(e, 2);
        e += __shfl_xor(e, 4);
        e += __shfl_xor(e, 8);
        const float lse = mx + __logf(e);
        float* op = out + (qbw + quad * 4 + reg) * 64 + m;
        op[0]  = s0 - lse;
        op[16] = s1 - lse;
        op[32] = s2 - lse;
        op[48] = s3 - lse;
    }
}

// ---------------------------------------------------------------------------
// ws layout (floats): [0, npart*16448) partial sums+counts | then pn_frags
// (32 KB, 16B-aligned).
// ---------------------------------------------------------------------------
extern "C" void kernel_launch(void* const* d_in, const int* in_sizes, int n_in,
                              void* d_out, int out_size, void* d_ws, size_t ws_size,
                              hipStream_t stream) {
    const float* support = (const float*)d_in[0];
    const int*   labels  = (const int*)d_in[1];
    const float* query   = (const float*)d_in[2];
    float* out = (float*)d_out;

    float* ws = (float*)d_ws;
    const int npart = (ws_size >= (size_t)16 * 16448 * 4 + 32768) ? 16 : 1;
    float* pa = ws;
    uint4* pn_frags = (uint4*)(ws + (size_t)npart * 16448);

    hipMemsetAsync(pa, 0, (size_t)npart * 16448 * sizeof(float), stream);

    seg_sum_kernel<<<256, 1024, 0, stream>>>(support, labels, pa, npart - 1);
    proto_norm_kernel<<<NCLS, 256, 0, stream>>>(pa, npart, pn_frags);
    query_kernel<<<NQ / 64, 256, 0, stream>>>(query, pn_frags, out);
}

// Round 2
// 475.837 us; speedup vs baseline: 1.4849x; 1.4793x over previous
//
#include <hip/hip_runtime.h>
#include <hip/hip_bf16.h>
#include <math.h>

#define NCLS 64
#define FDIM 256
#define EPS_F 1e-8f
#define NQ 131072
#define NS 262144

typedef __attribute__((ext_vector_type(8))) short short8;
typedef __attribute__((ext_vector_type(4))) float f32x4;

__device__ __forceinline__ unsigned short bf16bits(float f) {
    __hip_bfloat16 h = __float2bfloat16(f);
    return *reinterpret_cast<unsigned short*>(&h);
}

// ---------------------------------------------------------------------------
// Kernel A: segment-sum. 256 blocks x 1024 threads (16 waves), 1024 rows/blk.
//
// Round-1 diagnosis: three different inner loops (CAS atomicAdd, float4 +
// atomicAdd, raw ds_add_f32) ALL land at 357-365us => the LDS atomic RMW
// unit itself is the wall (~209 cyc per wave64 LDS atomic = 3.3 cyc/lane,
// serialized; VALUBusy 1%, HBM 5%). Fix: NO ATOMICS in the hot path.
//
// Class-ownership: wave w owns classes {4w..4w+3}; partial prototypes live
// in registers (4 x float4/lane = 16 VGPRs). Each wave ballot-compacts the
// block's 1024 labels into per-class index lists in its PRIVATE LDS region
// (no barriers, no sharing), then runs 4 dense per-class loops: each owned
// row is ONE coalesced 1KB global_load_dwordx4 (64 lanes x 16B) + 4 v_add.
// Every row is read exactly once by exactly one wave. BW floor: 1MB/CU at
// 10.25 B/cyc = 43us. Depth-2 prefetch; cadence (~1.6k cyc) >> 900cyc HBM
// latency. Flush: global unsafeAtomicAdd into npart partial buffers
// (unchanged; proven cheap).
// ---------------------------------------------------------------------------
__global__ __launch_bounds__(1024) void seg_sum_kernel(
    const float* __restrict__ support, const int* __restrict__ labels,
    float* __restrict__ pa, int set_mask)
{
    __shared__ unsigned short lists[16 * 1024];   // 32 KB: 1024 entries/wave
    const int tid  = threadIdx.x;
    const int lane = tid & 63;
    const int wave = tid >> 6;
    const int blk  = blockIdx.x;
    const size_t rowbase = (size_t)blk * 1024;

    // Block's 1024 labels: lane l holds labels[g*64+l] in lab[g].
    int lab[16];
    #pragma unroll
    for (int g = 0; g < 16; ++g)
        lab[g] = labels[rowbase + g * 64 + lane] & (NCLS - 1);

    const int wb = wave * 1024;     // this wave's private entry region

    // Pass 1: exact per-class counts (wave-uniform scalars).
    uint ncls[4] = {0u, 0u, 0u, 0u};
    #pragma unroll
    for (int c = 0; c < 4; ++c) {
        const int cls = wave * 4 + c;
        #pragma unroll
        for (int g = 0; g < 16; ++g)
            ncls[c] += (uint)__popcll(__ballot(lab[g] == cls));
    }
    uint ofs[4];
    ofs[0] = 0u;
    ofs[1] = ncls[0];
    ofs[2] = ncls[0] + ncls[1];
    ofs[3] = ncls[0] + ncls[1] + ncls[2];

    // Pass 2: compact row indices into per-class lists (exact offsets, safe
    // for ANY label distribution: sum of counts == 1024 == region size).
    #pragma unroll
    for (int c = 0; c < 4; ++c) {
        const int cls = wave * 4 + c;
        uint off = ofs[c];
        #pragma unroll
        for (int g = 0; g < 16; ++g) {
            const bool p = (lab[g] == cls);
            const unsigned long long mask = __ballot(p);
            if (p) {
                const uint below = __builtin_amdgcn_mbcnt_hi(
                    (uint)(mask >> 32),
                    __builtin_amdgcn_mbcnt_lo((uint)mask, 0u));
                lists[wb + off + below] = (unsigned short)(g * 64 + lane);
            }
            off += (uint)__popcll(mask);
        }
    }
    // No barrier: each wave reads only its own region; compiler tracks the
    // ds_write->ds_read dependency through the array.

    float* dst = pa + (size_t)(blk & set_mask) * 16448;
    const float4* s4 = (const float4*)support + rowbase * 64 + lane;

    // Accumulate + flush, one owned class at a time. Dense loop, depth-2
    // prefetch (issue load j while adding load j-1).
    #pragma unroll
    for (int c = 0; c < 4; ++c) {
        const uint n    = ncls[c];
        const uint base = (uint)wb + ofs[c];
        float4 a = make_float4(0.f, 0.f, 0.f, 0.f);
        if (n) {
            uint id = lists[base] & 1023u;
            float4 pp = s4[(size_t)id * 64];
            for (uint j = 1; j < n; ++j) {
                const uint idn = lists[base + j] & 1023u;
                const float4 qq = s4[(size_t)idn * 64];
                a.x += pp.x; a.y += pp.y; a.z += pp.z; a.w += pp.w;
                pp = qq;
            }
            a.x += pp.x; a.y += pp.y; a.z += pp.z; a.w += pp.w;
        }
        const int cls = wave * 4 + c;
        float* dp = dst + cls * FDIM + lane * 4;
        unsafeAtomicAdd(dp + 0, a.x);
        unsafeAtomicAdd(dp + 1, a.y);
        unsafeAtomicAdd(dp + 2, a.z);
        unsafeAtomicAdd(dp + 3, a.w);
    }

    // Counts: one atomic per owned class.
    if (lane == 0) {
        #pragma unroll
        for (int c = 0; c < 4; ++c)
            unsafeAtomicAdd(&dst[16384 + wave * 4 + c], (float)ncls[c]);
    }
}

// ---------------------------------------------------------------------------
// Kernel B: sum npart partials, normalize, emit Pn as bf16 B-FRAGMENTS for
// mfma_f32_16x16x32_bf16 (unchanged — verified correct).
// ---------------------------------------------------------------------------
__global__ __launch_bounds__(256) void proto_norm_kernel(
    const float* __restrict__ pa, int npart, uint4* __restrict__ pn_frags)
{
    __shared__ float pvec[FDIM];
    __shared__ float ssum[4];
    const int c = blockIdx.x;
    const int d = threadIdx.x;
    const int lane = d & 63;
    const int wv = d >> 6;

    float sum = 0.0f;
    #pragma unroll
    for (int s = 0; s < 16; ++s)
        if (s < npart) sum += pa[(size_t)s * 16448 + c * FDIM + d];

    float cv = (lane < npart) ? pa[(size_t)lane * 16448 + 16384 + c] : 0.0f;
    cv += __shfl_xor(cv, 1); cv += __shfl_xor(cv, 2);
    cv += __shfl_xor(cv, 4); cv += __shfl_xor(cv, 8);
    const float cnt = __shfl(cv, 0);

    const float p = sum / fmaxf(cnt, 1.0f);

    float ss = p * p;
    ss += __shfl_xor(ss, 1);  ss += __shfl_xor(ss, 2);
    ss += __shfl_xor(ss, 4);  ss += __shfl_xor(ss, 8);
    ss += __shfl_xor(ss, 16); ss += __shfl_xor(ss, 32);
    if (lane == 0) ssum[wv] = ss;
    __syncthreads();
    const float tot = ssum[0] + ssum[1] + ssum[2] + ssum[3];
    const float innv = 1.0f / fmaxf(sqrtf(tot), EPS_F);
    pvec[d] = p * innv;
    __syncthreads();

    if (d < 32) {
        const int kc = d >> 2, quad = d & 3;
        const float* pp = &pvec[kc * 32 + quad * 8];
        uint w0 = bf16bits(pp[0]) | ((uint)bf16bits(pp[1]) << 16);
        uint w1 = bf16bits(pp[2]) | ((uint)bf16bits(pp[3]) << 16);
        uint w2 = bf16bits(pp[4]) | ((uint)bf16bits(pp[5]) << 16);
        uint w3 = bf16bits(pp[6]) | ((uint)bf16bits(pp[7]) << 16);
        pn_frags[((c >> 4) * 8 + kc) * 64 + (c & 15) + 16 * quad] =
            make_uint4(w0, w1, w2, w3);
    }
}

// ---------------------------------------------------------------------------
// Kernel C: MFMA query GEMM + fused log_softmax (unchanged this round — will
// be the top dispatch once seg_sum drops to ~60us; attack with counters next).
// ---------------------------------------------------------------------------
#define QSTR 272   // bf16 elements per LDS row (544 B, multiple of 16 B)

__global__ __launch_bounds__(256) void query_kernel(
    const float* __restrict__ query, const uint4* __restrict__ pn_frags,
    float* __restrict__ out)
{
    __shared__ unsigned short Qb[64 * QSTR];   // 34816 B
    const int tid = threadIdx.x;
    const int lane = tid & 63;
    const int wave = tid >> 6;
    const size_t qb0 = (size_t)blockIdx.x * 64;

    // Stage: iteration i handles row i*4+wave; 64 lanes cover the whole row.
    #pragma unroll
    for (int i = 0; i < 16; ++i) {
        const int row = i * 4 + wave;
        const float4 v = ((const float4*)(query + (qb0 + row) * FDIM))[lane];
        const uint lo = bf16bits(v.x) | ((uint)bf16bits(v.y) << 16);
        const uint hi = bf16bits(v.z) | ((uint)bf16bits(v.w) << 16);
        *(uint2*)&Qb[row * QSTR + lane * 4] = make_uint2(lo, hi);
    }
    __syncthreads();

    const int m = lane & 15;
    const int quad = lane >> 4;
    const unsigned short* arow = &Qb[(wave * 16 + m) * QSTR + quad * 8];
    const short8* bp = (const short8*)pn_frags;

    f32x4 acc0 = {0.f,0.f,0.f,0.f}, acc1 = {0.f,0.f,0.f,0.f};
    f32x4 acc2 = {0.f,0.f,0.f,0.f}, acc3 = {0.f,0.f,0.f,0.f};
    float ssq = 0.0f;

    short8 a  = *(const short8*)(arow);
    short8 b0 = bp[(0 * 8 + 0) * 64 + lane];
    short8 b1 = bp[(1 * 8 + 0) * 64 + lane];
    short8 b2 = bp[(2 * 8 + 0) * 64 + lane];
    short8 b3 = bp[(3 * 8 + 0) * 64 + lane];

    #pragma unroll
    for (int kc = 0; kc < 8; ++kc) {
        short8 an, c0, c1, c2, c3;
        const int kn = (kc < 7) ? kc + 1 : 7;
        an = *(const short8*)(arow + kn * 32);
        c0 = bp[(0 * 8 + kn) * 64 + lane];
        c1 = bp[(1 * 8 + kn) * 64 + lane];
        c2 = bp[(2 * 8 + kn) * 64 + lane];
        c3 = bp[(3 * 8 + kn) * 64 + lane];

        // ||q|| partial from this lane's 8 bf16 elements (row m, quad slice).
        float x0 = __uint_as_float(((uint)(unsigned short)a[0]) << 16);
        float x1 = __uint_as_float(((uint)(unsigned short)a[1]) << 16);
        float x2 = __uint_as_float(((uint)(unsigned short)a[2]) << 16);
        float x3 = __uint_as_float(((uint)(unsigned short)a[3]) << 16);
        float x4 = __uint_as_float(((uint)(unsigned short)a[4]) << 16);
        float x5 = __uint_as_float(((uint)(unsigned short)a[5]) << 16);
        float x6 = __uint_as_float(((uint)(unsigned short)a[6]) << 16);
        float x7 = __uint_as_float(((uint)(unsigned short)a[7]) << 16);
        ssq = fmaf(x0, x0, ssq); ssq = fmaf(x1, x1, ssq);
        ssq = fmaf(x2, x2, ssq); ssq = fmaf(x3, x3, ssq);
        ssq = fmaf(x4, x4, ssq); ssq = fmaf(x5, x5, ssq);
        ssq = fmaf(x6, x6, ssq); ssq = fmaf(x7, x7, ssq);

        acc0 = __builtin_amdgcn_mfma_f32_16x16x32_bf16(a, b0, acc0, 0, 0, 0);
        acc1 = __builtin_amdgcn_mfma_f32_16x16x32_bf16(a, b1, acc1, 0, 0, 0);
        acc2 = __builtin_amdgcn_mfma_f32_16x16x32_bf16(a, b2, acc2, 0, 0, 0);
        acc3 = __builtin_amdgcn_mfma_f32_16x16x32_bf16(a, b3, acc3, 0, 0, 0);

        a = an; b0 = c0; b1 = c1; b2 = c2; b3 = c3;
    }

    // Combine quad slices: lane ends with full ssq of query row (lane&15).
    ssq += __shfl_xor(ssq, 16);
    ssq += __shfl_xor(ssq, 32);

    const size_t qbw = qb0 + wave * 16;
    #pragma unroll
    for (int reg = 0; reg < 4; ++reg) {
        const float rssq = __shfl(ssq, quad * 4 + reg);
        const float qs = 1.0f / fmaxf(sqrtf(rssq), EPS_F);
        float s0 = acc0[reg] * qs;
        float s1 = acc1[reg] * qs;
        float s2 = acc2[reg] * qs;
        float s3 = acc3[reg] * qs;
        float mx = fmaxf(fmaxf(s0, s1), fmaxf(s2, s3));
        mx = fmaxf(mx, __shfl_xor(mx, 1));
        mx = fmaxf(mx, __shfl_xor(mx, 2));
        mx = fmaxf(mx, __shfl_xor(mx, 4));
        mx = fmaxf(mx, __shfl_xor(mx, 8));
        float e = __expf(s0 - mx) + __expf(s1 - mx) +
                  __expf(s2 - mx) + __expf(s3 - mx);
        e += __shfl_xor(e, 1);
        e += __shfl_xor(e, 2);
        e += __shfl_xor(e, 4);
        e += __shfl_xor(e, 8);
        const float lse = mx + __logf(e);
        float* op = out + (qbw + quad * 4 + reg) * 64 + m;
        op[0]  = s0 - lse;
        op[16] = s1 - lse;
        op[32] = s2 - lse;
        op[48] = s3 - lse;
    }
}

// ---------------------------------------------------------------------------
// ws layout (floats): [0, npart*16448) partial sums+counts | then pn_frags
// (32 KB, 16B-aligned).
// ---------------------------------------------------------------------------
extern "C" void kernel_launch(void* const* d_in, const int* in_sizes, int n_in,
                              void* d_out, int out_size, void* d_ws, size_t ws_size,
                              hipStream_t stream) {
    const float* support = (const float*)d_in[0];
    const int*   labels  = (const int*)d_in[1];
    const float* query   = (const float*)d_in[2];
    float* out = (float*)d_out;

    float* ws = (float*)d_ws;
    const int npart = (ws_size >= (size_t)16 * 16448 * 4 + 32768) ? 16 : 1;
    float* pa = ws;
    uint4* pn_frags = (uint4*)(ws + (size_t)npart * 16448);

    hipMemsetAsync(pa, 0, (size_t)npart * 16448 * sizeof(float), stream);

    seg_sum_kernel<<<256, 1024, 0, stream>>>(support, labels, pa, npart - 1);
    proto_norm_kernel<<<NCLS, 256, 0, stream>>>(pa, npart, pn_frags);
    query_kernel<<<NQ / 64, 256, 0, stream>>>(query, pn_frags, out);
}